// Round 5
// baseline (51.352 us; speedup 1.0000x reference)
//
#include <hip/hip_runtime.h>

typedef unsigned int uint;
typedef unsigned short ushort;
typedef unsigned char uint8_t_;

constexpr int Bc = 4, Mc = 32, Hc = 152, Wc = 272;
constexpr int HWc = Hc * Wc;              // 41344
constexpr int WTc = 593;                  // (16+2)*16 + 16 + 16*16 + 16 + 16 + 1
constexpr int NB = 8;                     // blocks per (b,m)
constexpr int NEG_BLOCKS = Bc * Mc * NB;  // 1024
constexpr int ITERS = HWc / 64;           // 646 (exact)
constexpr int POS_OFF = 1024;             // ws float idx of pos terms
constexpr int WC_OFF = 2048;              // ws float idx of compact weights
constexpr int WC_STRIDE = 600;
constexpr int APK1_OFF = WC_OFF + 128 * WC_STRIDE;  // 78848
constexpr int APK2_OFF = APK1_OFF + 128 * 64 * 4;   // 111616
constexpr size_t XOFF_BYTES = (size_t)(APK2_OFF + 128 * 64 * 4) * 4;  // 577536
constexpr int GRPB = HWc / 16;            // 2584 pixel-groups per batch
constexpr int GSTRIDE = 576;              // bytes per 16-px group (256+256+64)
constexpr int XCVT_BLOCKS = 162 * Bc;     // 648

using f32x4 = __attribute__((ext_vector_type(4))) float;
using bf16x8 = __attribute__((ext_vector_type(8))) short;

__device__ inline uint pkbf(float lo, float hi) {
  uint r;
  asm("v_cvt_pk_bf16_f32 %0, %1, %2" : "=v"(r) : "v"(lo), "v"(hi));
  return r;
}
__device__ inline float bpermf(int byteaddr, float v) {
  return __int_as_float(__builtin_amdgcn_ds_bpermute(byteaddr, __float_as_int(v)));
}
__device__ inline uint bpermu(int byteaddr, uint v) {
  return (uint)__builtin_amdgcn_ds_bpermute(byteaddr, (int)v);
}

union FR { uint u[4]; bf16x8 v; };

// ---- fused pre-pass: xcvt blocks + prep/pos blocks ----
__global__ __launch_bounds__(256) void fused_pre(const float* __restrict__ sf_all,
                                                 const float* __restrict__ cw,
                                                 const int* __restrict__ pre_ind,
                                                 const int* __restrict__ ind,
                                                 const float* __restrict__ mask,
                                                 unsigned char* __restrict__ xb,
                                                 float* __restrict__ ws) {
  __shared__ float sw[WTc];
  const int blk = blockIdx.x, tid = threadIdx.x;

  if (blk < XCVT_BLOCKS) {
    // sch_feat fp32 [b][c][hw] -> bf16 tile-interleaved groups of 16 px:
    // [256B ch0-7][256B ch8-15][64B coords(x/128,y/128)]
    const int b = blk / 162, bx = blk - b * 162;
    const int px = bx * 256 + tid;
    if (px < HWc) {
      const float* s = sf_all + (size_t)b * 16 * HWc + px;
      uint q[8];
#pragma unroll
      for (int i = 0; i < 8; i++) q[i] = pkbf(s[(size_t)(2 * i) * HWc], s[(size_t)(2 * i + 1) * HWc]);
      const int hh = px / Wc, xx = px - hh * Wc;
      const uint q8 = pkbf((float)xx * 0.0078125f, (float)hh * 0.0078125f);
      const int grp = px >> 4, o = px & 15;
      unsigned char* gb = xb + ((size_t)b * GRPB + grp) * GSTRIDE;
      *(uint4*)(gb + o * 16) = make_uint4(q[0], q[1], q[2], q[3]);
      *(uint4*)(gb + 256 + o * 16) = make_uint4(q[4], q[5], q[6], q[7]);
      *(uint*)(gb + 512 + o * 4) = q8;
    }
    return;
  }

  // prep: gather 593 weights once per (b,m); pack A-fragments; pos term
  const int bm = blk - XCVT_BLOCKS, b = bm >> 5;
  const int p = pre_ind[bm];
  const float* wcol = cw + (size_t)b * WTc * HWc + p;
  float* wc = ws + WC_OFF + bm * WC_STRIDE;
  for (int j = tid; j < WTc; j += 256) {
    float v = wcol[(size_t)j * HWc];
    sw[j] = v;
    wc[j] = v;
  }
  __syncthreads();

  if (tid < 64) {
    const int g = tid >> 4, o = tid & 15;
    float a1f[8], a2f[8];
#pragma unroll
    for (int e = 0; e < 8; e++) {
      int k = 8 * g + e;
      a1f[e] = (k < 18) ? sw[o * 18 + k] : 0.0f;   // k=16,17 -> coord weights
      a2f[e] = (k < 16) ? sw[304 + o * 16 + k] : 0.0f;
    }
    uint4 u1, u2;
    u1.x = pkbf(a1f[0], a1f[1]); u1.y = pkbf(a1f[2], a1f[3]);
    u1.z = pkbf(a1f[4], a1f[5]); u1.w = pkbf(a1f[6], a1f[7]);
    u2.x = pkbf(a2f[0], a2f[1]); u2.y = pkbf(a2f[2], a2f[3]);
    u2.z = pkbf(a2f[4], a2f[5]); u2.w = pkbf(a2f[6], a2f[7]);
    ((uint4*)(ws + APK1_OFF))[bm * 64 + tid] = u1;
    ((uint4*)(ws + APK2_OFF))[bm * 64 + tid] = u2;
  } else if (tid == 64) {
    // positive-sample term, exact fp32
    const float* sf = sf_all + (size_t)b * 16 * HWc;
    const int pi = ind[bm];
    float f[18];
#pragma unroll
    for (int c = 0; c < 16; c++) f[c] = sf[(size_t)c * HWc + pi];
    const int hh = pi / Wc;
    const float x0 = (float)(p % Wc);
    const float y0 = (float)p / (float)Wc;
    f[16] = ((float)(pi - hh * Wc) - x0) * 0.0078125f;
    f[17] = ((float)hh - y0) * 0.0078125f;
    float h1[16];
    for (int oo = 0; oo < 16; oo++) {
      float a = sw[288 + oo];
#pragma unroll
      for (int c = 0; c < 18; c++) a = fmaf(sw[oo * 18 + c], f[c], a);
      h1[oo] = fmaxf(a, 0.0f);
    }
    float h2[16];
    for (int oo = 0; oo < 16; oo++) {
      float a = sw[560 + oo];
#pragma unroll
      for (int c = 0; c < 16; c++) a = fmaf(sw[304 + oo * 16 + c], h1[c], a);
      h2[oo] = fmaxf(a, 0.0f);
    }
    float zv = sw[592];
#pragma unroll
    for (int c = 0; c < 16; c++) zv = fmaf(sw[576 + c], h2[c], zv);
    float hm = __fdividef(1.0f, 1.0f + __expf(-zv));
    hm = fminf(fmaxf(hm, 1e-4f), 1.0f - 1e-4f);
    const float om = 1.0f - hm;
    ws[POS_OFF + bm] = __logf(hm) * om * om * mask[bm];
  }
}

// ---- main negative-loss kernel ----
__global__ __launch_bounds__(256, 4) void sch_neg(const float* __restrict__ target,
                                                  const unsigned char* __restrict__ xbf,
                                                  const int* __restrict__ pre_ind,
                                                  float* __restrict__ ws) {
  const int tid = threadIdx.x;
  const int lane = tid & 63;
  const int wid = tid >> 6;
  // XCD-aware swizzle: batch b pinned to XCD pair {2b, 2b+1}
  const int xcd = blockIdx.x & 7;
  const int slot = blockIdx.x >> 3;
  const int b = xcd >> 1;
  const int m = slot & 31;
  const int nb = ((slot >> 5) << 1) | (xcd & 1);
  const int bm = (b << 5) | m;
  const int g = lane >> 4;
  const int o = lane & 15;

  const int p = pre_ind[bm];
  const float x0 = (float)(p % Wc);
  const float y0 = (float)p / (float)Wc;  // float division of flat index (per reference)

  FR A1, A2;
  {
    uint4 u1 = ((const uint4*)(ws + APK1_OFF))[bm * 64 + lane];
    uint4 u2 = ((const uint4*)(ws + APK2_OFF))[bm * 64 + lane];
    A1.u[0] = u1.x; A1.u[1] = u1.y; A1.u[2] = u1.z; A1.u[3] = u1.w;
    A2.u[0] = u2.x; A2.u[1] = u2.y; A2.u[2] = u2.z; A2.u[3] = u2.w;
  }
  const float* wc = ws + WC_OFF + bm * WC_STRIDE;
  f32x4 c1v, c2v;
  float w3r[4];
#pragma unroll
  for (int r = 0; r < 4; r++) {
    int row = 4 * g + r;
    c1v[r] = wc[288 + row] - (wc[row * 18 + 16] * x0 + wc[row * 18 + 17] * y0) * 0.0078125f;
    c2v[r] = wc[560 + row];
    w3r[r] = wc[576 + row];
  }
  const float b3 = wc[592];

  const unsigned char* xb = xbf + (size_t)b * GRPB * GSTRIDE;
  const float* tg = target + (size_t)bm * HWc;

  const int aX16 = (lane ^ 16) << 2;
  const int aX32 = (lane ^ 32) << 2;
  const int aS0 = (o + ((g == 1) ? 32 : 0)) << 2;
  const int aS1 = (o + ((g == 1) ? 48 : 16)) << 2;
  const int offA = (g << 8) + (o << 4);   // g<2 main chunk offset
  const int offC = 512 + (o << 2);        // g==2 coord offset

  // B1 loader: g<2 -> dwordx4; g==2 -> dword (coords); g==3 -> zeros (A-slots zero)
  auto loadB1 = [&](int grpidx, uint4& q) {
    const unsigned char* gb = xb + (size_t)grpidx * GSTRIDE;
    if (g < 2) q = *(const uint4*)(gb + offA);
    else if (g == 2) q.x = *(const uint*)(gb + offC);
  };

  float acc = 0.0f;
  const int gw = nb * 4 + wid;

  uint4 ld[4];
  float tval;
#pragma unroll
  for (int c = 0; c < 4; c++) { ld[c] = make_uint4(0, 0, 0, 0); loadB1(gw * 4 + c, ld[c]); }
  tval = tg[gw * 64 + lane];

  for (int it = gw; it < ITERS; it += 32) {
    // software prefetch next iteration (hides L2/HBM latency under compute)
    const int nit = (it + 32 < ITERS) ? it + 32 : it;
    uint4 ldn[4];
    float tvn;
#pragma unroll
    for (int c = 0; c < 4; c++) { ldn[c] = make_uint4(0, 0, 0, 0); loadB1(nit * 4 + c, ldn[c]); }
    tvn = tg[nit * 64 + lane];

    float zpv[4];
#pragma unroll
    for (int half = 0; half < 2; half++) {
      FR B1a, B1b;
      B1a.u[0] = ld[2 * half].x; B1a.u[1] = ld[2 * half].y;
      B1a.u[2] = ld[2 * half].z; B1a.u[3] = ld[2 * half].w;
      B1b.u[0] = ld[2 * half + 1].x; B1b.u[1] = ld[2 * half + 1].y;
      B1b.u[2] = ld[2 * half + 1].z; B1b.u[3] = ld[2 * half + 1].w;
      f32x4 d1a = __builtin_amdgcn_mfma_f32_16x16x32_bf16(A1.v, B1a.v, c1v, 0, 0, 0);
      f32x4 d1b = __builtin_amdgcn_mfma_f32_16x16x32_bf16(A1.v, B1b.v, c1v, 0, 0, 0);
      uint pa0 = pkbf(fmaxf(d1a[0], 0.0f), fmaxf(d1a[1], 0.0f));
      uint pa1 = pkbf(fmaxf(d1a[2], 0.0f), fmaxf(d1a[3], 0.0f));
      uint pb0 = pkbf(fmaxf(d1b[0], 0.0f), fmaxf(d1b[1], 0.0f));
      uint pb1 = pkbf(fmaxf(d1b[2], 0.0f), fmaxf(d1b[3], 0.0f));
      FR B2a, B2b;
      B2a.u[0] = bpermu(aS0, pa0); B2a.u[1] = bpermu(aS0, pa1);
      B2a.u[2] = bpermu(aS1, pa0); B2a.u[3] = bpermu(aS1, pa1);
      B2b.u[0] = bpermu(aS0, pb0); B2b.u[1] = bpermu(aS0, pb1);
      B2b.u[2] = bpermu(aS1, pb0); B2b.u[3] = bpermu(aS1, pb1);
      f32x4 d2a = __builtin_amdgcn_mfma_f32_16x16x32_bf16(A2.v, B2a.v, c2v, 0, 0, 0);
      f32x4 d2b = __builtin_amdgcn_mfma_f32_16x16x32_bf16(A2.v, B2b.v, c2v, 0, 0, 0);
      zpv[2 * half] = fmaxf(d2a[0], 0.0f) * w3r[0] + fmaxf(d2a[1], 0.0f) * w3r[1] +
                      fmaxf(d2a[2], 0.0f) * w3r[2] + fmaxf(d2a[3], 0.0f) * w3r[3];
      zpv[2 * half + 1] = fmaxf(d2b[0], 0.0f) * w3r[0] + fmaxf(d2b[1], 0.0f) * w3r[1] +
                          fmaxf(d2b[2], 0.0f) * w3r[2] + fmaxf(d2b[3], 0.0f) * w3r[3];
    }
    // packed 2-round transpose-reduce: S(pixel base+lane) = sum_g zpv
    const int b0 = g & 1, b1 = g & 2;
    const float pk_g  = b1 ? (b0 ? zpv[3] : zpv[2]) : (b0 ? zpv[1] : zpv[0]);
    const float pk_g1 = b1 ? (b0 ? zpv[2] : zpv[3]) : (b0 ? zpv[0] : zpv[1]);
    const float pk_g2 = b1 ? (b0 ? zpv[1] : zpv[0]) : (b0 ? zpv[3] : zpv[2]);
    const float pk_g3 = b1 ? (b0 ? zpv[0] : zpv[1]) : (b0 ? zpv[2] : zpv[3]);
    const float tA = pk_g + bpermf(aX16, pk_g1);
    const float tB = pk_g2 + bpermf(aX16, pk_g3);
    const float S = tA + bpermf(aX32, tB);

    const float zz = S + b3;
    float hm = __fdividef(1.0f, 1.0f + __expf(-zz));
    hm = fminf(fmaxf(hm, 1e-4f), 1.0f - 1e-4f);
    const float u = 1.0f - tval;
    const float u2 = u * u;
    acc += __logf(1.0f - hm) * hm * hm * (u2 * u2);

#pragma unroll
    for (int c = 0; c < 4; c++) ld[c] = ldn[c];
    tval = tvn;
  }

  __shared__ float red[256];
  red[tid] = acc;
  __syncthreads();
  for (int s = 128; s > 0; s >>= 1) {
    if (tid < s) red[tid] += red[tid + s];
    __syncthreads();
  }
  if (tid == 0) ws[blockIdx.x] = red[0];
}

// ---- final reduction ----
__global__ __launch_bounds__(256) void sch_final(const float* __restrict__ ws,
                                                 const float* __restrict__ mask,
                                                 float* __restrict__ out) {
  __shared__ float red[256];
  const int t = threadIdx.x;

  float s = 0.0f;
  for (int i = t; i < NEG_BLOCKS; i += 256) s += ws[i];
  red[t] = s; __syncthreads();
  for (int k = 128; k > 0; k >>= 1) { if (t < k) red[t] += red[t + k]; __syncthreads(); }
  const float neg = red[0];
  __syncthreads();

  float pv = (t < Bc * Mc) ? ws[POS_OFF + t] : 0.0f;
  red[t] = pv; __syncthreads();
  for (int k = 128; k > 0; k >>= 1) { if (t < k) red[t] += red[t + k]; __syncthreads(); }
  const float pos = red[0];
  __syncthreads();

  float mv = (t < Bc * Mc) ? mask[t] : 0.0f;
  red[t] = mv; __syncthreads();
  for (int k = 128; k > 0; k >>= 1) { if (t < k) red[t] += red[t + k]; __syncthreads(); }

  if (t == 0) {
    float np = red[0];
    out[0] = (np == 0.0f) ? (-neg) : (-(pos + neg) / fmaxf(np, 1.0f));
  }
}

extern "C" void kernel_launch(void* const* d_in, const int* in_sizes, int n_in,
                              void* d_out, int out_size, void* d_ws, size_t ws_size,
                              hipStream_t stream) {
  const float* sch_feat    = (const float*)d_in[0];
  const float* conv_weight = (const float*)d_in[1];
  const float* mask        = (const float*)d_in[2];
  const int*   pre_ind     = (const int*)d_in[3];
  const float* target      = (const float*)d_in[4];
  const int*   ind         = (const int*)d_in[5];
  float* out = (float*)d_out;
  float* ws  = (float*)d_ws;
  unsigned char* xbf = (unsigned char*)d_ws + XOFF_BYTES;

  fused_pre<<<dim3(XCVT_BLOCKS + Bc * Mc), dim3(256), 0, stream>>>(
      sch_feat, conv_weight, pre_ind, ind, mask, xbf, ws);
  sch_neg<<<dim3(NEG_BLOCKS), dim3(256), 0, stream>>>(target, xbf, pre_ind, ws);
  sch_final<<<dim3(1), dim3(256), 0, stream>>>(ws, mask, out);
}

// Round 6
// 50.077 us; speedup vs baseline: 1.0255x; 1.0255x over previous
//
#include <hip/hip_runtime.h>

typedef unsigned int uint;
typedef unsigned short ushort;

constexpr int Bc = 4, Mc = 32, Hc = 152, Wc = 272;
constexpr int HWc = Hc * Wc;              // 41344
constexpr int WTc = 593;                  // (16+2)*16 + 16 + 16*16 + 16 + 16 + 1
constexpr int NB = 8;                     // blocks per (b,m)
constexpr int NEG_BLOCKS = Bc * Mc * NB;  // 1024
constexpr int ITERS = HWc / 64;           // 646 (exact)
constexpr int POS_OFF = 1024;             // ws float idx of pos terms
constexpr int WC_OFF = 2048;              // ws float idx of compact weights
constexpr int WC_STRIDE = 600;
constexpr int APK1_OFF = WC_OFF + 128 * WC_STRIDE;  // 78848
constexpr int APK2_OFF = APK1_OFF + 128 * 64 * 4;   // 111616
constexpr size_t XOFF_BYTES = (size_t)(APK2_OFF + 128 * 64 * 4) * 4;  // 577536
constexpr int GRPB = HWc / 16;            // 2584 pixel-groups per batch
constexpr int GSTRIDE = 576;              // bytes per 16-px group (256+256+64)
constexpr int XCVT_BLOCKS = 162 * Bc;     // 648

using f32x4 = __attribute__((ext_vector_type(4))) float;
using bf16x8 = __attribute__((ext_vector_type(8))) short;

__device__ inline uint pkbf(float lo, float hi) {
  uint r;
  asm("v_cvt_pk_bf16_f32 %0, %1, %2" : "=v"(r) : "v"(lo), "v"(hi));
  return r;
}

// convention-immune cross-half sums: pr[0]+pr[1] == x[l] + x[l^K] for self-swap
__device__ inline float xsum16(float x) {
#if __has_builtin(__builtin_amdgcn_permlane16_swap)
  uint u = __float_as_uint(x);
  auto pr = __builtin_amdgcn_permlane16_swap(u, u, false, false);
  return __uint_as_float(pr[0]) + __uint_as_float(pr[1]);
#else
  return x + __shfl_xor(x, 16);
#endif
}
__device__ inline float xsum32(float x) {
#if __has_builtin(__builtin_amdgcn_permlane32_swap)
  uint u = __float_as_uint(x);
  auto pr = __builtin_amdgcn_permlane32_swap(u, u, false, false);
  return __uint_as_float(pr[0]) + __uint_as_float(pr[1]);
#else
  return x + __shfl_xor(x, 32);
#endif
}

union FR { uint u[4]; bf16x8 v; };

// ---- fused pre-pass: xcvt blocks + prep/pos blocks ----
__global__ __launch_bounds__(256) void fused_pre(const float* __restrict__ sf_all,
                                                 const float* __restrict__ cw,
                                                 const int* __restrict__ pre_ind,
                                                 const int* __restrict__ ind,
                                                 const float* __restrict__ mask,
                                                 unsigned char* __restrict__ xb,
                                                 float* __restrict__ ws) {
  __shared__ float sw[WTc];
  const int blk = blockIdx.x, tid = threadIdx.x;

  if (blk < XCVT_BLOCKS) {
    // sch_feat fp32 [b][c][hw] -> bf16 tile-interleaved groups of 16 px:
    // [256B ch0-7][256B ch8-15][64B coords(x/128,y/128)]
    const int b = blk / 162, bx = blk - b * 162;
    const int px = bx * 256 + tid;
    if (px < HWc) {
      const float* s = sf_all + (size_t)b * 16 * HWc + px;
      uint q[8];
#pragma unroll
      for (int i = 0; i < 8; i++) q[i] = pkbf(s[(size_t)(2 * i) * HWc], s[(size_t)(2 * i + 1) * HWc]);
      const int hh = px / Wc, xx = px - hh * Wc;
      const uint q8 = pkbf((float)xx * 0.0078125f, (float)hh * 0.0078125f);
      const int grp = px >> 4, o = px & 15;
      unsigned char* gb = xb + ((size_t)b * GRPB + grp) * GSTRIDE;
      *(uint4*)(gb + o * 16) = make_uint4(q[0], q[1], q[2], q[3]);
      *(uint4*)(gb + 256 + o * 16) = make_uint4(q[4], q[5], q[6], q[7]);
      *(uint*)(gb + 512 + o * 4) = q8;
    }
    return;
  }

  // prep: gather 593 weights once per (b,m); pack A-fragments; pos term
  const int bm = blk - XCVT_BLOCKS, b = bm >> 5;
  const int p = pre_ind[bm];
  const float* wcol = cw + (size_t)b * WTc * HWc + p;
  float* wc = ws + WC_OFF + bm * WC_STRIDE;
  for (int j = tid; j < WTc; j += 256) {
    float v = wcol[(size_t)j * HWc];
    sw[j] = v;
    wc[j] = v;
  }
  __syncthreads();

  if (tid < 64) {
    const int g = tid >> 4, o = tid & 15;
    float a1f[8], a2f[8];
#pragma unroll
    for (int e = 0; e < 8; e++) {
      int k = 8 * g + e;
      a1f[e] = (k < 18) ? sw[o * 18 + k] : 0.0f;   // k=16,17 -> coord weights
      // A2 matched to D1's native distribution: group g carries channels 4g..4g+3
      a2f[e] = (e < 4) ? sw[304 + o * 16 + 4 * g + e] : 0.0f;
    }
    uint4 u1, u2;
    u1.x = pkbf(a1f[0], a1f[1]); u1.y = pkbf(a1f[2], a1f[3]);
    u1.z = pkbf(a1f[4], a1f[5]); u1.w = pkbf(a1f[6], a1f[7]);
    u2.x = pkbf(a2f[0], a2f[1]); u2.y = pkbf(a2f[2], a2f[3]);
    u2.z = pkbf(a2f[4], a2f[5]); u2.w = pkbf(a2f[6], a2f[7]);
    ((uint4*)(ws + APK1_OFF))[bm * 64 + tid] = u1;
    ((uint4*)(ws + APK2_OFF))[bm * 64 + tid] = u2;
  } else if (tid == 64) {
    // positive-sample term, exact fp32
    const float* sf = sf_all + (size_t)b * 16 * HWc;
    const int pi = ind[bm];
    float f[18];
#pragma unroll
    for (int c = 0; c < 16; c++) f[c] = sf[(size_t)c * HWc + pi];
    const int hh = pi / Wc;
    const float x0 = (float)(p % Wc);
    const float y0 = (float)p / (float)Wc;
    f[16] = ((float)(pi - hh * Wc) - x0) * 0.0078125f;
    f[17] = ((float)hh - y0) * 0.0078125f;
    float h1[16];
    for (int oo = 0; oo < 16; oo++) {
      float a = sw[288 + oo];
#pragma unroll
      for (int c = 0; c < 18; c++) a = fmaf(sw[oo * 18 + c], f[c], a);
      h1[oo] = fmaxf(a, 0.0f);
    }
    float h2[16];
    for (int oo = 0; oo < 16; oo++) {
      float a = sw[560 + oo];
#pragma unroll
      for (int c = 0; c < 16; c++) a = fmaf(sw[304 + oo * 16 + c], h1[c], a);
      h2[oo] = fmaxf(a, 0.0f);
    }
    float zv = sw[592];
#pragma unroll
    for (int c = 0; c < 16; c++) zv = fmaf(sw[576 + c], h2[c], zv);
    float hm = __fdividef(1.0f, 1.0f + __expf(-zv));
    hm = fminf(fmaxf(hm, 1e-4f), 1.0f - 1e-4f);
    const float om = 1.0f - hm;
    ws[POS_OFF + bm] = __logf(hm) * om * om * mask[bm];
  }
}

// ---- main negative-loss kernel: zero DS ops in the hot loop ----
__global__ __launch_bounds__(256, 4) void sch_neg(const float* __restrict__ target,
                                                  const unsigned char* __restrict__ xbf,
                                                  const int* __restrict__ pre_ind,
                                                  float* __restrict__ ws) {
  const int tid = threadIdx.x;
  const int lane = tid & 63;
  const int wid = tid >> 6;
  // XCD-aware swizzle: batch b pinned to XCD pair {2b, 2b+1}
  const int xcd = blockIdx.x & 7;
  const int slot = blockIdx.x >> 3;
  const int b = xcd >> 1;
  const int m = slot & 31;
  const int nb = ((slot >> 5) << 1) | (xcd & 1);
  const int bm = (b << 5) | m;
  const int g = lane >> 4;
  const int o = lane & 15;

  const int p = pre_ind[bm];
  const float x0 = (float)(p % Wc);
  const float y0 = (float)p / (float)Wc;  // float division of flat index (per reference)

  FR A1, A2;
  {
    uint4 u1 = ((const uint4*)(ws + APK1_OFF))[bm * 64 + lane];
    uint4 u2 = ((const uint4*)(ws + APK2_OFF))[bm * 64 + lane];
    A1.u[0] = u1.x; A1.u[1] = u1.y; A1.u[2] = u1.z; A1.u[3] = u1.w;
    A2.u[0] = u2.x; A2.u[1] = u2.y; A2.u[2] = u2.z; A2.u[3] = u2.w;
  }
  const float* wc = ws + WC_OFF + bm * WC_STRIDE;
  f32x4 c1v, c2v;
  float w3r[4];
#pragma unroll
  for (int r = 0; r < 4; r++) {
    int row = 4 * g + r;
    c1v[r] = wc[288 + row] - (wc[row * 18 + 16] * x0 + wc[row * 18 + 17] * y0) * 0.0078125f;
    c2v[r] = wc[560 + row];
    w3r[r] = wc[576 + row];
  }
  const float b3 = wc[592];

  const unsigned char* xb = xbf + (size_t)b * GRPB * GSTRIDE;
  const float* tg = target + (size_t)bm * HWc;

  // loop-invariant uniform load offset: g<2 -> channel chunk; g>=2 -> coord dwords
  const int addrOff = (g < 2) ? ((g << 8) + (o << 4)) : (512 + (o << 2));

  float acc = 0.0f;
  const int gw = nb * 4 + wid;
  for (int it = gw; it < ITERS; it += 32) {
    const unsigned char* gb = xb + (size_t)(it * 4) * GSTRIDE;
    uint4 ld[4];
#pragma unroll
    for (int c = 0; c < 4; c++) ld[c] = *(const uint4*)(gb + c * GSTRIDE + addrOff);
    const float tval = tg[it * 64 + lane];

    float Z[4];
#pragma unroll
    for (int c = 0; c < 4; c++) {
      FR B1;
      B1.u[0] = ld[c].x; B1.u[1] = ld[c].y; B1.u[2] = ld[c].z; B1.u[3] = ld[c].w;
      f32x4 d1 = __builtin_amdgcn_mfma_f32_16x16x32_bf16(A1.v, B1.v, c1v, 0, 0, 0);
      FR B2;
      B2.u[0] = pkbf(fmaxf(d1[0], 0.0f), fmaxf(d1[1], 0.0f));
      B2.u[1] = pkbf(fmaxf(d1[2], 0.0f), fmaxf(d1[3], 0.0f));
      B2.u[2] = 0u;
      B2.u[3] = 0u;
      f32x4 d2 = __builtin_amdgcn_mfma_f32_16x16x32_bf16(A2.v, B2.v, c2v, 0, 0, 0);
      float zp = fmaxf(d2[0], 0.0f) * w3r[0] + fmaxf(d2[1], 0.0f) * w3r[1] +
                 fmaxf(d2[2], 0.0f) * w3r[2] + fmaxf(d2[3], 0.0f) * w3r[3];
      Z[c] = xsum32(xsum16(zp));  // full 4-way reduce over channel groups (VALU pipe)
    }
    // lane l handles pixel it*64 + l (chain c = l>>4, column j = l&15)
    float zz = (lane & 32) ? ((lane & 16) ? Z[3] : Z[2]) : ((lane & 16) ? Z[1] : Z[0]);
    zz += b3;
    float hm = __fdividef(1.0f, 1.0f + __expf(-zz));
    hm = fminf(fmaxf(hm, 1e-4f), 1.0f - 1e-4f);
    const float u = 1.0f - tval;
    const float u2 = u * u;
    acc += __logf(1.0f - hm) * hm * hm * (u2 * u2);
  }

  __shared__ float red[256];
  red[tid] = acc;
  __syncthreads();
  for (int s = 128; s > 0; s >>= 1) {
    if (tid < s) red[tid] += red[tid + s];
    __syncthreads();
  }
  if (tid == 0) ws[blockIdx.x] = red[0];
}

// ---- final reduction ----
__global__ __launch_bounds__(256) void sch_final(const float* __restrict__ ws,
                                                 const float* __restrict__ mask,
                                                 float* __restrict__ out) {
  __shared__ float red[256];
  const int t = threadIdx.x;

  float s = 0.0f;
  for (int i = t; i < NEG_BLOCKS; i += 256) s += ws[i];
  red[t] = s; __syncthreads();
  for (int k = 128; k > 0; k >>= 1) { if (t < k) red[t] += red[t + k]; __syncthreads(); }
  const float neg = red[0];
  __syncthreads();

  float pv = (t < Bc * Mc) ? ws[POS_OFF + t] : 0.0f;
  red[t] = pv; __syncthreads();
  for (int k = 128; k > 0; k >>= 1) { if (t < k) red[t] += red[t + k]; __syncthreads(); }
  const float pos = red[0];
  __syncthreads();

  float mv = (t < Bc * Mc) ? mask[t] : 0.0f;
  red[t] = mv; __syncthreads();
  for (int k = 128; k > 0; k >>= 1) { if (t < k) red[t] += red[t + k]; __syncthreads(); }

  if (t == 0) {
    float np = red[0];
    out[0] = (np == 0.0f) ? (-neg) : (-(pos + neg) / fmaxf(np, 1.0f));
  }
}

extern "C" void kernel_launch(void* const* d_in, const int* in_sizes, int n_in,
                              void* d_out, int out_size, void* d_ws, size_t ws_size,
                              hipStream_t stream) {
  const float* sch_feat    = (const float*)d_in[0];
  const float* conv_weight = (const float*)d_in[1];
  const float* mask        = (const float*)d_in[2];
  const int*   pre_ind     = (const int*)d_in[3];
  const float* target      = (const float*)d_in[4];
  const int*   ind         = (const int*)d_in[5];
  float* out = (float*)d_out;
  float* ws  = (float*)d_ws;
  unsigned char* xbf = (unsigned char*)d_ws + XOFF_BYTES;

  fused_pre<<<dim3(XCVT_BLOCKS + Bc * Mc), dim3(256), 0, stream>>>(
      sch_feat, conv_weight, pre_ind, ind, mask, xbf, ws);
  sch_neg<<<dim3(NEG_BLOCKS), dim3(256), 0, stream>>>(target, xbf, pre_ind, ws);
  sch_final<<<dim3(1), dim3(256), 0, stream>>>(ws, mask, out);
}